// Round 2
// baseline (712.425 us; speedup 1.0000x reference)
//
#include <hip/hip_runtime.h>

// Downsample2d: depthwise 4x4 blur (separable taps 1/8,3/8,3/8,1/8),
// stride 2, reflect pad 1.
// x: (8,256,256,256) fp32 -> out: (8,256,128,128) fp32.
// HBM floor: ~544 MiB read (incl. strip overlap) + 128 MiB write ~= 110 us @ 6.3 TB/s.
//
// R3: pure streaming, no LDS, no barrier.
//   R1/R2 post-mortem: occupancy & LDS-traffic changes were a no-op, so the
//   wall is the shared phase structure (stage -> vmcnt(0)+barrier -> compute).
//   Here each WAVE independently owns a 16-output-row strip of one plane:
//     - one global float4 load per lane = one full 256-col input row per wave
//     - horizontal blur in registers (2 __shfl for the cross-lane taps,
//       reflect handled at lanes 0/63)
//     - vertical blur via a 2-row rolling register window (each H row used
//       by 2 output rows, loaded exactly once)
//     - float2 stores: wave covers one full 128-col output row (512 B)
//   No __syncthreads, no vmcnt(0) drain points, loads freely pipelined.

#define K0 0.125f
#define K1 0.375f

__global__ __launch_bounds__(256, 8) void downsample2d_kernel(
    const float* __restrict__ x, float* __restrict__ out)
{
    const int tid   = threadIdx.x;
    const int lane  = tid & 63;
    const int gw    = (blockIdx.x << 2) + (tid >> 6);  // global wave id, 0..16383
    const int strip = gw & 7;                          // 8 strips of 16 output rows
    const int plane = gw >> 3;                         // b*C + c, 0..2047
    const int oh0   = strip << 4;
    const int ir0   = (oh0 << 1) - 1;                  // first input row of strip

    const float* xp = x + (size_t)plane * (256 * 256);
    float* op = out + (size_t)plane * (128 * 128)
                    + (size_t)oh0 * 128 + (lane << 1);

    const int c4 = lane << 2;                          // this lane's 4 input cols

    // Load input row (local index r, reflect-clamped) and return the two
    // horizontal-blur values for output cols 2*lane, 2*lane+1.
    auto loadH = [&](int r) -> float2 {
        int gr = ir0 + r;
        gr = (gr < 0) ? 1 : ((gr > 255) ? 254 : gr);   // reflect rows (-1->1, 256->254)
        float4 v = *(const float4*)(xp + (gr << 8) + c4);
        float xm1 = __shfl_up(v.w, 1);                 // col 4*lane - 1
        float xp4 = __shfl_down(v.x, 1);               // col 4*lane + 4
        if (lane == 0)  xm1 = v.y;                     // reflect col -1  -> 1
        if (lane == 63) xp4 = v.z;                     // reflect col 256 -> 254
        return make_float2(K0 * xm1 + K1 * v.x + K1 * v.y + K0 * v.z,
                           K0 * v.y + K1 * v.z + K1 * v.w + K0 * xp4);
    };

    float2 hA = loadH(0);
    float2 hB = loadH(1);
    #pragma unroll 4
    for (int l = 0; l < 16; ++l) {
        float2 hC = loadH(2 * l + 2);
        float2 hD = loadH(2 * l + 3);
        float2 o;
        o.x = K0 * hA.x + K1 * hB.x + K1 * hC.x + K0 * hD.x;
        o.y = K0 * hA.y + K1 * hB.y + K1 * hC.y + K0 * hD.y;
        *(float2*)(op + l * 128) = o;                  // 512 B contiguous per wave
        hA = hC;
        hB = hD;
    }
}

extern "C" void kernel_launch(void* const* d_in, const int* in_sizes, int n_in,
                              void* d_out, int out_size, void* d_ws, size_t ws_size,
                              hipStream_t stream) {
    const float* x = (const float*)d_in[0];
    // d_in[1] is the 4x4 kernel == outer([1/8,3/8,3/8,1/8]) exactly; taps hardcoded.
    float* out = (float*)d_out;

    const int planes = 8 * 256;                // B*C
    const int waves  = planes * 8;             // 8 strips per plane, 1 wave each
    const int blocks = waves / 4;              // 4 waves per 256-thread block
    downsample2d_kernel<<<blocks, 256, 0, stream>>>(x, out);
}